// Round 11
// baseline (291.291 us; speedup 1.0000x reference)
//
#include <hip/hip_runtime.h>

#define HID 1024
#define SEQ 2048
#define NB 4
#define BS 8192  // NB*SEQ

typedef __attribute__((ext_vector_type(8))) short short8;
typedef __attribute__((ext_vector_type(8))) unsigned short ushort8;
typedef __attribute__((ext_vector_type(4))) float f32x4;

__device__ __forceinline__ float bf2f(unsigned short u) {
  unsigned int x = ((unsigned int)u) << 16;
  return __builtin_bit_cast(float, x);
}
__device__ __forceinline__ unsigned short f2bf(float f) {
  unsigned int x = __builtin_bit_cast(unsigned int, f);
  x = x + 0x7fffu + ((x >> 16) & 1u);
  return (unsigned short)(x >> 16);
}

#define GLOAD16(g, l)                                                          \
  __builtin_amdgcn_global_load_lds(                                            \
      (const __attribute__((address_space(1))) unsigned int*)(g),              \
      (__attribute__((address_space(3))) unsigned int*)(l), 16, 0, 0)

// ---------------- fp32 -> bf16 cast, 8 elems/thread ----------------
__global__ void cast_f32_to_bf16(const float* __restrict__ in,
                                 unsigned short* __restrict__ out, int n) {
  int i = (blockIdx.x * 256 + threadIdx.x) * 8;
  if (i >= n) return;
  f32x4 a = *(const f32x4*)(in + i);
  f32x4 b = *(const f32x4*)(in + i + 4);
  ushort8 o;
  o[0] = f2bf(a[0]); o[1] = f2bf(a[1]); o[2] = f2bf(a[2]); o[3] = f2bf(a[3]);
  o[4] = f2bf(b[0]); o[5] = f2bf(b[1]); o[6] = f2bf(b[2]); o[7] = f2bf(b[3]);
  *(ushort8*)(out + i) = o;
}

// ------------- 1024x1024 fp32 -> bf16 transposed cast -------------
__global__ __launch_bounds__(256) void transpose_cast(
    const float* __restrict__ in, unsigned short* __restrict__ out) {
  __shared__ float t[32][33];
  const int bx = blockIdx.x * 32, by = blockIdx.y * 32;
  const int tx = threadIdx.x & 31, ty = threadIdx.x >> 5;  // 32 x 8
#pragma unroll
  for (int i = 0; i < 4; ++i)
    t[ty + i * 8][tx] = in[(by + ty + i * 8) * 1024 + bx + tx];
  __syncthreads();
#pragma unroll
  for (int i = 0; i < 4; ++i)
    out[(bx + ty + i * 8) * 1024 + by + tx] = f2bf(t[tx][ty + i * 8]);
}

// ------------- b'[h] = bo[h] + sum_k Wo[h,k] * bv[k] -------------
__global__ __launch_bounds__(256) void bias_fuse(const float* __restrict__ Wo,
                                                 const float* __restrict__ bv,
                                                 const float* __restrict__ bo,
                                                 float* __restrict__ bp) {
  const int row = blockIdx.x * 4 + (threadIdx.x >> 6);
  const int lane = threadIdx.x & 63;
  float s = 0.f;
  for (int k = lane; k < 1024; k += 64) s += Wo[row * 1024 + k] * bv[k];
#pragma unroll
  for (int off = 32; off >= 1; off >>= 1) s += __shfl_xor(s, off, 64);
  if (lane == 0) bp[row] = s + bo[row];
}

// ------------- vvec[a] = sum_h Wk[h,a] * bq[h] (coalesced over a) ---------
__global__ __launch_bounds__(256) void col_gemv(const float* __restrict__ W,
                                                const float* __restrict__ b,
                                                float* __restrict__ out) {
  const int a = blockIdx.x * 256 + threadIdx.x;
  float s = 0.f;
  for (int h = 0; h < 1024; ++h) s += W[h * 1024 + a] * b[h];
  out[a] = s;
}

// ------------- c = bq . bk -------------
__global__ void dot_bias(const float* __restrict__ bq,
                         const float* __restrict__ bk, float* __restrict__ c) {
  __shared__ float red[4];
  const int tid = threadIdx.x;
  float s = 0.f;
  for (int i = tid; i < 1024; i += 256) s += bq[i] * bk[i];
#pragma unroll
  for (int o = 32; o >= 1; o >>= 1) s += __shfl_xor(s, o, 64);
  if ((tid & 63) == 0) red[tid >> 6] = s;
  __syncthreads();
  if (tid == 0) c[0] = red[0] + red[1] + red[2] + red[3];
}

// ------------- cb[j] = (x_j . vvec + c) / 32 -------------
__global__ __launch_bounds__(256) void row_gemv_cb(const float* __restrict__ x,
                                                   const float* __restrict__ v,
                                                   const float* __restrict__ c,
                                                   float* __restrict__ cb) {
  const int j = blockIdx.x * 4 + (threadIdx.x >> 6);
  const int lane = threadIdx.x & 63;
  float s = 0.f;
  for (int a = lane; a < 1024; a += 64) s += x[(long long)j * 1024 + a] * v[a];
#pragma unroll
  for (int o = 32; o >= 1; o >>= 1) s += __shfl_xor(s, o, 64);
  if (lane == 0) cb[j] = (s + c[0]) * 0.03125f;
}

// ================== 128x128 TLP NT GEMM (BK=32) ============================
// C[m,n] = alpha * sum_k A[m,k]*B[n,k]. 256 thr = 4 waves (2x2), 64x64/wave.
// Double-buffered 32KB LDS, 3 blocks/CU (round-6 config: best TLP number),
// round-7 0-conflict XOR swizzle (phys 16B-slot = logical ^ row bits 1-2;
// global source col pre-swizzled, ds_read offsets XOR'd - rule 21).
// BIAS_MODE: 0 none, 1 bias[col], 4 bias[bz*SEQ+col] (pre-exp col bias).
// EPI: 0 plain, 1 exp(v)+rowsum->Srow atomics, 2 scale by 1/Srow.
// Epilogue order: alpha -> (EPI2: /Srow) -> +bias -> (EPI1: exp).
template <int OUT_F32, int BIAS_MODE, int EPI>
__global__ __launch_bounds__(256, 3) void gemm_tlp(
    const unsigned short* __restrict__ A, const unsigned short* __restrict__ B,
    void* __restrict__ Cv, const float* __restrict__ bias,
    float* __restrict__ Srow, int K, int lda, int ldb, int ldc, long long bsA,
    long long bsB, long long bsC, float alpha) {
  __shared__ unsigned short lA[2][128 * 32];
  __shared__ unsigned short lB[2][128 * 32];

  const int tid = threadIdx.x;
  const int lane = tid & 63, wid = tid >> 6;
  const int fr = lane & 15, fq = lane >> 4;
  const int wm = wid >> 1, wn = wid & 1;

  // XCD-aware chunked swizzle on flattened (y,x); all grids have nwg%8==0.
  const int nx = gridDim.x;
  const int nwg = nx * gridDim.y;
  int f = blockIdx.y * nx + blockIdx.x;
  f = (f & 7) * (nwg >> 3) + (f >> 3);
  const int bx = f % nx, by = f / nx;
  const int bz = blockIdx.z;

  const unsigned short* Ag = A + bz * bsA + (long long)by * 128 * lda;
  const unsigned short* Bg = B + bz * bsB + (long long)bx * 128 * ldb;
  const int NT = K >> 5;  // K multiple of 64 -> NT even

  // Staging: LDS dest linear (wave-uniform base + lane*16B). Global source
  // column pre-swizzled: phys slot (tid&3) holds logical (tid&3)^((row>>1)&3).
  const int srow = tid >> 2;
  const int scol = 8 * ((tid & 3) ^ ((tid >> 3) & 3));
  const int lbase = wid * 512;  // ushorts, wave-uniform

  auto stageA = [&](int t, int b) {
    unsigned short* d = &lA[b][lbase];
    GLOAD16(Ag + (long long)srow * lda + t * 32 + scol, d);
    GLOAD16(Ag + (long long)(64 + srow) * lda + t * 32 + scol, d + 2048);
  };
  auto stageB = [&](int t, int b) {
    unsigned short* d = &lB[b][lbase];
    GLOAD16(Bg + (long long)srow * ldb + t * 32 + scol, d);
    GLOAD16(Bg + (long long)(64 + srow) * ldb + t * 32 + scol, d + 2048);
  };

  // ds_read offsets: XOR the 16B-slot with row bits 1-2 (= fr bits 1-2).
  const int xm = ((fr >> 1) & 3) << 3;  // ushort-unit mask (bits 3-4)

  f32x4 acc[4][4] = {};

  auto compute = [&](const unsigned short* pa, const unsigned short* pb) {
    short8 av[4], bw[4];
#pragma unroll
    for (int i = 0; i < 4; ++i)
      av[i] = *(const short8*)(pa +
                               (((wm * 64 + i * 16 + fr) * 32 + fq * 8) ^ xm));
#pragma unroll
    for (int n = 0; n < 4; ++n)
      bw[n] = *(const short8*)(pb +
                               (((wn * 64 + n * 16 + fr) * 32 + fq * 8) ^ xm));
#pragma unroll
    for (int i = 0; i < 4; ++i)
#pragma unroll
      for (int n = 0; n < 4; ++n)
        acc[i][n] = __builtin_amdgcn_mfma_f32_16x16x32_bf16(av[i], bw[n],
                                                            acc[i][n], 0, 0, 0);
  };

  stageA(0, 0);
  stageB(0, 0);
  __syncthreads();

  for (int t = 0; t < NT; t += 2) {
    stageA(t + 1, 1);
    stageB(t + 1, 1);
    compute(lA[0], lB[0]);
    __syncthreads();  // drains vm (publishes buf1) + closes buf0 reads
    if (t + 2 < NT) {
      stageA(t + 2, 0);
      stageB(t + 2, 0);
    }
    compute(lA[1], lB[1]);
    __syncthreads();
  }

  // Epilogue. C/D frag layout: col = 16*frag + fr, row = fq*4 + j.
  const long long cb0 = (long long)bz * bsC;
  float* sredf = (float*)lA;  // [128][2] row-sum scratch (EPI==1)
#pragma unroll
  for (int i = 0; i < 4; ++i)
#pragma unroll
    for (int j = 0; j < 4; ++j) {
      const int row = wm * 64 + i * 16 + fq * 4 + j;
      float inv = 1.0f;
      if (EPI == 2) inv = 1.0f / Srow[(long long)bz * SEQ + by * 128 + row];
      float rps = 0.0f;
#pragma unroll
      for (int n = 0; n < 4; ++n) {
        const int col = bx * 128 + wn * 64 + n * 16 + fr;
        float v = acc[i][n][j] * alpha;
        if (EPI == 2) v *= inv;
        if (BIAS_MODE == 1) v += bias[col];
        if (BIAS_MODE == 4) v += bias[(long long)bz * SEQ + col];
        if (EPI == 1) { v = __expf(v); rps += v; }
        const long long idx = cb0 + (long long)(by * 128 + row) * ldc + col;
        if (OUT_F32)
          ((float*)Cv)[idx] = v;
        else
          ((unsigned short*)Cv)[idx] = f2bf(v);
      }
      if (EPI == 1) {
        rps += __shfl_xor(rps, 1, 64);
        rps += __shfl_xor(rps, 2, 64);
        rps += __shfl_xor(rps, 4, 64);
        rps += __shfl_xor(rps, 8, 64);
        if (fr == 0) sredf[row * 2 + wn] = rps;
      }
    }
  if (EPI == 1) {
    __syncthreads();
    if (tid < 128) {
      const float s2 = sredf[tid * 2] + sredf[tid * 2 + 1];
      atomicAdd(Srow + (long long)bz * SEQ + by * 128 + tid, s2);
    }
  }
}

extern "C" void kernel_launch(void* const* d_in, const int* in_sizes, int n_in,
                              void* d_out, int out_size, void* d_ws,
                              size_t ws_size, hipStream_t stream) {
  (void)in_sizes; (void)n_in; (void)out_size; (void)ws_size;
  const float* x = (const float*)d_in[0];
  const float* Wq = (const float*)d_in[1];
  const float* bq = (const float*)d_in[2];
  const float* Wk = (const float*)d_in[3];
  const float* bk = (const float*)d_in[4];
  const float* Wv = (const float*)d_in[5];
  const float* bv = (const float*)d_in[6];
  const float* Wo = (const float*)d_in[7];
  const float* bo = (const float*)d_in[8];
  float* out = (float*)d_out;

  char* ws = (char*)d_ws;
  unsigned short* xbf  = (unsigned short*)(ws + 0);         // 16 MiB
  unsigned short* WqT  = (unsigned short*)(ws + 16777216);  // 2 MiB
  unsigned short* WkT  = (unsigned short*)(ws + 18874368);  // 2 MiB
  unsigned short* wvT  = (unsigned short*)(ws + 20971520);  // 2 MiB
  unsigned short* wobf = (unsigned short*)(ws + 23068672);  // 2 MiB
  unsigned short* GT   = (unsigned short*)(ws + 25165824);  // 2 MiB (G^T)
  unsigned short* wov  = (unsigned short*)(ws + 27262976);  // 2 MiB (Wo.Wv)
  float*          bpr  = (float*)        (ws + 29360128);   // 4 KiB
  float*          vvec = (float*)        (ws + 29425664);   // 4 KiB (Wk^T bq)
  float*          cdot = (float*)        (ws + 29491200);   // 4 B  (bq.bk)
  float*          cb   = (float*)        (ws + 29556736);   // 32 KiB col bias
  float*          Srow = (float*)        (ws + 29622272);   // 32 KiB rowsums
  unsigned short* U    = (unsigned short*)(ws + 33554432);  // 16 MiB [8192][1024]
  unsigned short* VWoT = (unsigned short*)(ws + 50331648);  // 16 MiB [1024][8192]
  unsigned short* P    = (unsigned short*)(ws + 67108864);  // 32 MiB [4][2048][2048]
  // total 100,663,296 bytes

  // casts & small precomputes
  cast_f32_to_bf16<<<4096, 256, 0, stream>>>(x, xbf, BS * HID);
  transpose_cast<<<dim3(32, 32), 256, 0, stream>>>(Wq, WqT);
  transpose_cast<<<dim3(32, 32), 256, 0, stream>>>(Wk, WkT);
  transpose_cast<<<dim3(32, 32), 256, 0, stream>>>(Wv, wvT);
  cast_f32_to_bf16<<<512, 256, 0, stream>>>(Wo, wobf, HID * HID);
  bias_fuse<<<256, 256, 0, stream>>>(Wo, bv, bo, bpr);
  col_gemv<<<4, 256, 0, stream>>>(Wk, bq, vvec);
  dot_bias<<<1, 256, 0, stream>>>(bq, bk, cdot);
  hipMemsetAsync(Srow, 0, NB * SEQ * sizeof(float), stream);

  // GT[b,a] = sum_o Wk[o,b] Wq[o,a] = NT(WkT, WqT) : [1024,1024] (= G^T)
  gemm_tlp<0, 0, 0><<<dim3(8, 8, 1), 256, 0, stream>>>(
      WkT, WqT, GT, nullptr, nullptr, HID, HID, HID, HID, 0, 0, 0, 1.0f);
  // wov[h,k] = sum_j Wo[h,j] Wv[j,k] = NT(wobf, wvT) : [1024,1024]
  gemm_tlp<0, 0, 0><<<dim3(8, 8, 1), 256, 0, stream>>>(
      wobf, wvT, wov, nullptr, nullptr, HID, HID, HID, HID, 0, 0, 0, 1.0f);
  // U[i,b] = sum_a x[i,a] G[a,b] = NT(xbf, GT) : [8192,1024]
  gemm_tlp<0, 0, 0><<<dim3(8, 64, 1), 256, 0, stream>>>(
      xbf, GT, U, nullptr, nullptr, HID, HID, HID, HID, 0, 0, 0, 1.0f);
  // cb[j] = (x_j . vvec + bq.bk) / 32  (surviving softmax column bias)
  row_gemv_cb<<<2048, 256, 0, stream>>>(x, vvec, cdot, cb);
  // VWoT[h,s] = sum_k wov[h,k] x[s,k] = NT(wov, xbf) : [1024,8192]
  gemm_tlp<0, 0, 0><<<dim3(64, 8, 1), 256, 0, stream>>>(
      wov, xbf, VWoT, nullptr, nullptr, HID, HID, HID, BS, 0, 0, 0, 1.0f);
  // P = exp(U x^T / 32 + cb_j) per batch + rowsums : [4][2048][2048]
  gemm_tlp<0, 4, 1><<<dim3(16, 16, NB), 256, 0, stream>>>(
      U, xbf, P, cb, Srow, HID, HID, HID, SEQ, (long long)SEQ * HID,
      (long long)SEQ * HID, (long long)SEQ * SEQ, 0.03125f);
  // out = (P @ VWoT^T) / Srow + b' : [8192,1024] fp32 (k-window via bsB)
  gemm_tlp<1, 1, 2><<<dim3(8, 16, NB), 256, 0, stream>>>(
      P, VWoT, out, bpr, Srow, SEQ, SEQ, BS, HID, (long long)SEQ * SEQ,
      (long long)SEQ, (long long)SEQ * HID, 1.0f);
}

// Round 12
// 215.398 us; speedup vs baseline: 1.3523x; 1.3523x over previous
//
#include <hip/hip_runtime.h>

#define HID 1024
#define SEQ 2048
#define NB 4
#define BS 8192  // NB*SEQ

typedef __attribute__((ext_vector_type(8))) short short8;
typedef __attribute__((ext_vector_type(8))) unsigned short ushort8;
typedef __attribute__((ext_vector_type(4))) float f32x4;

__device__ __forceinline__ float bf2f(unsigned short u) {
  unsigned int x = ((unsigned int)u) << 16;
  return __builtin_bit_cast(float, x);
}
__device__ __forceinline__ unsigned short f2bf(float f) {
  unsigned int x = __builtin_bit_cast(unsigned int, f);
  x = x + 0x7fffu + ((x >> 16) & 1u);
  return (unsigned short)(x >> 16);
}

#define GLOAD16(g, l)                                                          \
  __builtin_amdgcn_global_load_lds(                                            \
      (const __attribute__((address_space(1))) unsigned int*)(g),              \
      (__attribute__((address_space(3))) unsigned int*)(l), 16, 0, 0)

// ---------------- fp32 -> bf16 cast, 8 elems/thread ----------------
__global__ void cast_f32_to_bf16(const float* __restrict__ in,
                                 unsigned short* __restrict__ out, int n) {
  int i = (blockIdx.x * 256 + threadIdx.x) * 8;
  if (i >= n) return;
  f32x4 a = *(const f32x4*)(in + i);
  f32x4 b = *(const f32x4*)(in + i + 4);
  ushort8 o;
  o[0] = f2bf(a[0]); o[1] = f2bf(a[1]); o[2] = f2bf(a[2]); o[3] = f2bf(a[3]);
  o[4] = f2bf(b[0]); o[5] = f2bf(b[1]); o[6] = f2bf(b[2]); o[7] = f2bf(b[3]);
  *(ushort8*)(out + i) = o;
}

// ------------- 1024x1024 fp32 -> bf16 transposed cast -------------
__global__ __launch_bounds__(256) void transpose_cast(
    const float* __restrict__ in, unsigned short* __restrict__ out) {
  __shared__ float t[32][33];
  const int bx = blockIdx.x * 32, by = blockIdx.y * 32;
  const int tx = threadIdx.x & 31, ty = threadIdx.x >> 5;  // 32 x 8
#pragma unroll
  for (int i = 0; i < 4; ++i)
    t[ty + i * 8][tx] = in[(by + ty + i * 8) * 1024 + bx + tx];
  __syncthreads();
#pragma unroll
  for (int i = 0; i < 4; ++i)
    out[(bx + ty + i * 8) * 1024 + by + tx] = f2bf(t[tx][ty + i * 8]);
}

// ------------- b'[h] = bo[h] + sum_k Wo[h,k] * bv[k] -------------
__global__ __launch_bounds__(256) void bias_fuse(const float* __restrict__ Wo,
                                                 const float* __restrict__ bv,
                                                 const float* __restrict__ bo,
                                                 float* __restrict__ bp) {
  const int row = blockIdx.x * 4 + (threadIdx.x >> 6);
  const int lane = threadIdx.x & 63;
  float s = 0.f;
  for (int k = lane; k < 1024; k += 64) s += Wo[row * 1024 + k] * bv[k];
#pragma unroll
  for (int off = 32; off >= 1; off >>= 1) s += __shfl_xor(s, off, 64);
  if (lane == 0) bp[row] = s + bo[row];
}

// ========== 256 x BN 2-phase NT GEMM (BK=64, 8 waves) — T3 minimal =========
// C[m,n] = alpha * sum_k A[m,k]*B[n,k] (+bias). 512 thr = 8 waves.
// BN=256: waves 2Mx4N (tile 128x64); BN=128: waves 4Mx2N (tile 64x64).
// Guide's verified minimal 2-phase recipe (m230-V0 = 682 TF):
//   stage(t+1) FIRST; per k-half {reads once, lgkmcnt(0)+sched_barrier
//   (rule 18), setprio(1)+MFMA}; ONE vmcnt(0)+s_barrier per K-tile.
// Fragments read exactly once per K-tile (unlike round-2's quadrant scheme).
// LDS swizzle for 128B rows (G4 recipe): 16B-slot ^= (row&7); inverse-swz
// global source, XOR'd ds_read slot (rule 21). 2 lanes/bank-quad = free.
// BIAS_MODE: 0 none, 1 bias[col], 3 col<1024?bias:bias2.
// EPI: 0 plain, 1 exp(v)+rowsum->Srow atomics, 2 scale by 1/Srow.
template <int BN, int OUT_F32, int BIAS_MODE, int EPI>
__global__ __launch_bounds__(512, 2) void gemm2p(
    const unsigned short* __restrict__ A, const unsigned short* __restrict__ B,
    void* __restrict__ Cv, const float* __restrict__ bias,
    const float* __restrict__ bias2, float* __restrict__ Srow, int K, int lda,
    int ldb, int ldc, long long bsA, long long bsB, long long bsC,
    float alpha) {
  static_assert(BN == 256 || BN == 128, "BN");
  constexpr int WMW = (BN == 256) ? 2 : 4;  // waves along M
  constexpr int WNW = 8 / WMW;              // waves along N
  constexpr int MI = (256 / WMW) / 16;      // M frags/wave (8 or 4)
  constexpr int GB = BN / 64;               // B gloads per stage (4 or 2)
  constexpr int WROWS = 256 / WMW;          // wave M span (128 or 64)

  __shared__ unsigned short lA[2][256 * 64];  // 64 KB
  __shared__ unsigned short lB[2][BN * 64];   // 64 or 32 KB

  const int tid = threadIdx.x;
  const int lane = tid & 63, wid = tid >> 6;
  const int fr = lane & 15, fq = lane >> 4;
  const int wm = wid / WNW, wn = wid % WNW;

  // XCD-aware chunked swizzle on flattened (y,x); all grids have nwg%8==0.
  const int nx = gridDim.x;
  const int nwg = nx * gridDim.y;
  int f = blockIdx.y * nx + blockIdx.x;
  f = (f & 7) * (nwg >> 3) + (f >> 3);
  const int bx = f % nx, by = f / nx;
  const int bz = blockIdx.z;

  const unsigned short* Ag = A + bz * bsA + (long long)by * 256 * lda;
  const unsigned short* Bg = B + bz * bsB + (long long)bx * BN * ldb;
  const int NT = K >> 6;

  // Stage geometry: thread covers 16B. LDS linear dest (wave-uniform base,
  // HW adds lane*16B): row = c*64 + tid>>3, phys slot = tid&7. Global source
  // uses logical slot = phys ^ (row&7) -> the LDS image is slot-swizzled.
  const int srow = tid >> 3;
  const int gcol = 8 * ((tid & 7) ^ ((tid >> 3) & 7));
  const int ldst = wid * 512;  // ushorts, wave-uniform

  auto stage = [&](int t) {
    const int b = t & 1;
#pragma unroll
    for (int c = 0; c < 4; ++c)
      GLOAD16(Ag + (long long)(c * 64 + srow) * lda + t * 64 + gcol,
              &lA[b][c * 4096 + ldst]);
#pragma unroll
    for (int c = 0; c < GB; ++c)
      GLOAD16(Bg + (long long)(c * 64 + srow) * ldb + t * 64 + gcol,
              &lB[b][c * 4096 + ldst]);
  };

  const int rxor = fr & 7;  // row&7 for fragment rows (bases are 16-aligned)
  f32x4 acc[MI][4] = {};

  auto phase = [&](const unsigned short* pa, const unsigned short* pb,
                   int kk) {
    short8 av[MI], bw[4];
    const int slot = ((kk << 2) | fq) ^ rxor;
#pragma unroll
    for (int i = 0; i < MI; ++i)
      av[i] = *(const short8*)(pa + (wm * WROWS + i * 16 + fr) * 64 + slot * 8);
#pragma unroll
    for (int n = 0; n < 4; ++n)
      bw[n] = *(const short8*)(pb + (wn * 64 + n * 16 + fr) * 64 + slot * 8);
    asm volatile("s_waitcnt lgkmcnt(0)" ::: "memory");
    __builtin_amdgcn_sched_barrier(0);
    __builtin_amdgcn_s_setprio(1);
#pragma unroll
    for (int i = 0; i < MI; ++i)
#pragma unroll
      for (int n = 0; n < 4; ++n)
        acc[i][n] = __builtin_amdgcn_mfma_f32_16x16x32_bf16(av[i], bw[n],
                                                            acc[i][n], 0, 0, 0);
    __builtin_amdgcn_s_setprio(0);
  };

  stage(0);
  asm volatile("s_waitcnt vmcnt(0)" ::: "memory");
  __builtin_amdgcn_s_barrier();

  for (int t = 0; t < NT; ++t) {
    if (t + 1 < NT) stage(t + 1);  // issue BEFORE compute (T3 recipe)
    const unsigned short* pa = lA[t & 1];
    const unsigned short* pb = lB[t & 1];
    phase(pa, pb, 0);
    phase(pa, pb, 1);
    asm volatile("s_waitcnt vmcnt(0)" ::: "memory");  // next tile landed
    __builtin_amdgcn_s_barrier();                     // one barrier per tile
  }

  // Epilogue. C/D frag layout: col = 16*frag + fr, row = fq*4 + j.
  const long long cb0 = (long long)bz * bsC;
  float* sredf = (float*)lA;  // [256][WNW] row-sum scratch (EPI==1)
#pragma unroll
  for (int i = 0; i < MI; ++i)
#pragma unroll
    for (int j = 0; j < 4; ++j) {
      const int row = wm * WROWS + i * 16 + fq * 4 + j;
      float inv = 1.0f;
      if (EPI == 2) inv = 1.0f / Srow[(long long)bz * SEQ + by * 256 + row];
      float rps = 0.0f;
#pragma unroll
      for (int n = 0; n < 4; ++n) {
        const int col = bx * BN + wn * 64 + n * 16 + fr;
        float v = acc[i][n][j] * alpha;
        if (EPI == 2) v *= inv;
        if (BIAS_MODE == 1) v += bias[col];
        if (BIAS_MODE == 3) v += (col < 1024) ? bias[col] : bias2[col - 1024];
        if (EPI == 1) { v = __expf(v); rps += v; }
        const long long idx = cb0 + (long long)(by * 256 + row) * ldc + col;
        if (OUT_F32)
          ((float*)Cv)[idx] = v;
        else
          ((unsigned short*)Cv)[idx] = f2bf(v);
      }
      if (EPI == 1) {
        rps += __shfl_xor(rps, 1, 64);
        rps += __shfl_xor(rps, 2, 64);
        rps += __shfl_xor(rps, 4, 64);
        rps += __shfl_xor(rps, 8, 64);
        if (fr == 0) sredf[row * WNW + wn] = rps;
      }
    }
  if (EPI == 1) {
    __syncthreads();
    if (tid < 256) {
      float s = 0.f;
#pragma unroll
      for (int w = 0; w < WNW; ++w) s += sredf[tid * WNW + w];
      atomicAdd(Srow + (long long)bz * SEQ + by * 256 + tid, s);
    }
  }
}

extern "C" void kernel_launch(void* const* d_in, const int* in_sizes, int n_in,
                              void* d_out, int out_size, void* d_ws,
                              size_t ws_size, hipStream_t stream) {
  (void)in_sizes; (void)n_in; (void)out_size; (void)ws_size;
  const float* x = (const float*)d_in[0];
  const float* Wq = (const float*)d_in[1];
  const float* bq = (const float*)d_in[2];
  const float* Wk = (const float*)d_in[3];
  const float* bk = (const float*)d_in[4];
  const float* Wv = (const float*)d_in[5];
  const float* bv = (const float*)d_in[6];
  const float* Wo = (const float*)d_in[7];
  const float* bo = (const float*)d_in[8];
  float* out = (float*)d_out;

  char* ws = (char*)d_ws;
  unsigned short* xbf  = (unsigned short*)(ws + 0);         // 16 MiB
  unsigned short* wqk  = (unsigned short*)(ws + 16777216);  // 4 MiB [2048][1024]
  unsigned short* wobf = (unsigned short*)(ws + 20971520);  // 2 MiB
  unsigned short* wvT  = (unsigned short*)(ws + 23068672);  // 2 MiB (Wv^T)
  unsigned short* wov  = (unsigned short*)(ws + 25165824);  // 2 MiB (Wo.Wv)
  float*          bpr  = (float*)        (ws + 27262976);   // 4 KiB (Wo.bv+bo)
  float*          Srow = (float*)        (ws + 28311552);   // 32 KiB rowsums
  unsigned short* VWoT = (unsigned short*)(ws + 33554432);  // 16 MiB [1024][8192]
  unsigned short* QKb  = (unsigned short*)(ws + 50331648);  // 32 MiB [8192][2048]
  unsigned short* P    = (unsigned short*)(ws + 83886080);  // 32 MiB [4][2048][2048]

  // casts & small precomputes (round-6 dataflow, best measured)
  cast_f32_to_bf16<<<4096, 256, 0, stream>>>(x, xbf, BS * HID);
  cast_f32_to_bf16<<<512, 256, 0, stream>>>(Wq, wqk, HID * HID);
  cast_f32_to_bf16<<<512, 256, 0, stream>>>(Wk, wqk + HID * HID, HID * HID);
  cast_f32_to_bf16<<<512, 256, 0, stream>>>(Wo, wobf, HID * HID);
  transpose_cast<<<dim3(32, 32), 256, 0, stream>>>(Wv, wvT);
  bias_fuse<<<256, 256, 0, stream>>>(Wo, bv, bo, bpr);
  hipMemsetAsync(Srow, 0, NB * SEQ * sizeof(float), stream);

  // wov[h,k] = sum_j Wo[h,j] Wv[j,k] = NT(wobf, wvT) : [1024,1024]
  gemm2p<128, 0, 0, 0><<<dim3(8, 4, 1), 512, 0, stream>>>(
      wobf, wvT, wov, nullptr, nullptr, nullptr, HID, HID, HID, HID, 0, 0, 0,
      1.0f);
  // VWoT[h,s] = sum_k wov[h,k] x[s,k] = NT(wov, xbf) : [1024,8192]
  gemm2p<128, 0, 0, 0><<<dim3(64, 4, 1), 512, 0, stream>>>(
      wov, xbf, VWoT, nullptr, nullptr, nullptr, HID, HID, HID, BS, 0, 0, 0,
      1.0f);
  // [Q|K] = x @ [Wq;Wk]^T + [bq;bk] : [8192,2048]
  gemm2p<256, 0, 3, 0><<<dim3(8, 32, 1), 512, 0, stream>>>(
      xbf, wqk, QKb, bq, bk, nullptr, HID, HID, HID, 2048, 0, 0, 0, 1.0f);
  // P = exp(Q @ K^T / 32) per batch + rowsums : [4][2048][2048]
  gemm2p<256, 0, 0, 1><<<dim3(8, 8, NB), 512, 0, stream>>>(
      QKb, QKb + 1024, P, nullptr, nullptr, Srow, HID, 2048, 2048, SEQ,
      (long long)SEQ * 2048, (long long)SEQ * 2048, (long long)SEQ * SEQ,
      0.03125f);
  // out = (P @ VWoT^T) / Srow + b' : [8192,1024] fp32 (k-window via bsB)
  gemm2p<128, 1, 1, 2><<<dim3(8, 8, NB), 512, 0, stream>>>(
      P, VWoT, out, bpr, nullptr, Srow, SEQ, SEQ, BS, HID,
      (long long)SEQ * SEQ, (long long)SEQ, (long long)SEQ * HID, 1.0f);
}